// Round 2
// baseline (2786.821 us; speedup 1.0000x reference)
//
#include <hip/hip_runtime.h>
#include <cmath>

// Problem constants (from reference)
#define S_LEN 2048
#define B_SZ 32
#define D_DIM 512
#define H_DIM 512
#define C_NUM 10
#define M_ROWS (S_LEN * B_SZ)   // 65536
#define BH (B_SZ * H_DIM)       // 16384 (= 2^14)
#define N_COLS (3 * H_DIM)      // 1536
#define CH2 32                  // subchunk length for the parallel scan

// ---------------- gather: h[m][d] = embed[x[m]][d] ----------------
__global__ void gather_kernel(const int* __restrict__ x,
                              const float4* __restrict__ embed4,
                              float4* __restrict__ h4) {
  int i = blockIdx.x * blockDim.x + threadIdx.x;
  const int total = M_ROWS * (D_DIM / 4);
  int stride = gridDim.x * blockDim.x;
  for (; i < total; i += stride) {
    int m = i >> 7;      // D/4 = 128
    int d = i & 127;
    h4[i] = embed4[(size_t)x[m] * 128 + d];
  }
}

// ---------------- SGEMM + gate epilogue ----------------
// C = A(rows x 512) * W(512 x 1536); cols [0,512)->xt, [512,1024)->f=sig(+bf), [1024,1536)->r=sig(+br)
#define BM 128
#define BN 128
#define BK 8
#define PAD_BM 132

__global__ __launch_bounds__(256) void sru_gemm(
    const float* __restrict__ A, const float* __restrict__ Wl,
    const float* __restrict__ bl,
    float* __restrict__ xt_out, float* __restrict__ f_out, float* __restrict__ r_out) {
  __shared__ float As[BK][PAD_BM];
  __shared__ float Bs[BK][BN];

  int bid = blockIdx.x;
  int nb = bid % (N_COLS / BN);  // 12, fastest -> A-tile reuse in L2/L3
  int mb = bid / (N_COLS / BN);
  int m0 = mb * BM;
  int n0 = nb * BN;
  int t = threadIdx.x;
  int tx = t & 15;
  int ty = t >> 4;

  int a_row = t >> 1;
  int a_cg = (t & 1) * 4;
  int b_k = t >> 5;
  int b_c = (t & 31) * 4;

  float acc[8][8];
#pragma unroll
  for (int i = 0; i < 8; i++)
#pragma unroll
    for (int j = 0; j < 8; j++) acc[i][j] = 0.f;

  const float* Aptr = A + (size_t)(m0 + a_row) * D_DIM + a_cg;
  const float* Bptr = Wl + (size_t)b_k * N_COLS + n0 + b_c;

  for (int k0 = 0; k0 < D_DIM; k0 += BK) {
    float4 av = *(const float4*)(Aptr);
    float4 bv = *(const float4*)(Bptr);
    __syncthreads();
    As[a_cg + 0][a_row] = av.x;
    As[a_cg + 1][a_row] = av.y;
    As[a_cg + 2][a_row] = av.z;
    As[a_cg + 3][a_row] = av.w;
    *(float4*)&Bs[b_k][b_c] = bv;
    __syncthreads();
#pragma unroll
    for (int kk = 0; kk < BK; kk++) {
      float4 a0 = *(const float4*)&As[kk][ty * 8];
      float4 a1 = *(const float4*)&As[kk][ty * 8 + 4];
      float4 b0 = *(const float4*)&Bs[kk][tx * 4];
      float4 b1 = *(const float4*)&Bs[kk][64 + tx * 4];
      float a_[8] = {a0.x, a0.y, a0.z, a0.w, a1.x, a1.y, a1.z, a1.w};
      float b_[8] = {b0.x, b0.y, b0.z, b0.w, b1.x, b1.y, b1.z, b1.w};
#pragma unroll
      for (int i = 0; i < 8; i++)
#pragma unroll
        for (int j = 0; j < 8; j++) acc[i][j] = fmaf(a_[i], b_[j], acc[i][j]);
    }
    Aptr += BK;
    Bptr += (size_t)BK * N_COLS;
  }

  int region = n0 >> 9;               // 0=xt, 1=f, 2=r
  int nloc0 = (n0 & 511) + tx * 4;
  float* outp = (region == 0) ? xt_out : ((region == 1) ? f_out : r_out);
  float bias0[4], bias1[4];
  if (region > 0) {
    const float* bptr = bl + (region == 2 ? 512 : 0);
#pragma unroll
    for (int j = 0; j < 4; j++) {
      bias0[j] = bptr[nloc0 + j];
      bias1[j] = bptr[nloc0 + 64 + j];
    }
  }
#pragma unroll
  for (int i = 0; i < 8; i++) {
    size_t row = (size_t)(m0 + ty * 8 + i) * H_DIM;
    float v0[4], v1[4];
#pragma unroll
    for (int j = 0; j < 4; j++) {
      v0[j] = acc[i][j];
      v1[j] = acc[i][4 + j];
    }
    if (region > 0) {
#pragma unroll
      for (int j = 0; j < 4; j++) {
        v0[j] = 1.f / (1.f + __expf(-(v0[j] + bias0[j])));
        v1[j] = 1.f / (1.f + __expf(-(v1[j] + bias1[j])));
      }
    }
    *(float4*)&outp[row + nloc0] = make_float4(v0[0], v0[1], v0[2], v0[3]);
    *(float4*)&outp[row + nloc0 + 64] = make_float4(v1[0], v1[1], v1[2], v1[3]);
  }
}

// ---------------- chunk-parallel linear scan over one outer chunk ----------------
// pass1: per (subchunk, b, h): A = prod f, B = local scan with c0=0
__global__ void scan_pass1(const float* __restrict__ f, const float* __restrict__ xt,
                           float* __restrict__ Ac, float* __restrict__ Bc) {
  int gid = blockIdx.x * blockDim.x + threadIdx.x;  // nsub*BH
  int ch = gid >> 14;
  int rem = gid & (BH - 1);
  size_t base = (size_t)ch * CH2 * BH + rem;
  const float* fp = f + base;
  const float* xp = xt + base;
  float Aacc = 1.f, Bacc = 0.f;
#pragma unroll 8
  for (int s = 0; s < CH2; s++) {
    float fv = fp[(size_t)s * BH];
    float xv = xp[(size_t)s * BH];
    Bacc = fv * Bacc + (1.f - fv) * xv;
    Aacc *= fv;
  }
  Ac[gid] = Aacc;
  Bc[gid] = Bacc;
}

// pass2: sequential combine of subchunk composites -> carry-in per subchunk.
// Carry state threads across outer chunks via cstate (reset when first=1).
__global__ void scan_carry(const float* __restrict__ Ac, const float* __restrict__ Bc,
                           float* __restrict__ carry, float* __restrict__ cstate,
                           int nsub, int first) {
  int rem = blockIdx.x * blockDim.x + threadIdx.x;  // BH
  float c = first ? 0.f : cstate[rem];
  for (int ch = 0; ch < nsub; ch++) {
    int idx = ch * BH + rem;
    carry[idx] = c;
    c = Ac[idx] * c + Bc[idx];
  }
  cstate[rem] = c;
}

// pass3: apply with correct carry, write highway output in-place over h chunk,
// optionally fold a running max (keyed by gid; first outer chunk initializes).
template <int DO_MAX>
__global__ void scan_pass2(const float* __restrict__ f, const float* __restrict__ xt,
                           const float* __restrict__ r, float* __restrict__ h,
                           const float* __restrict__ carry, float* __restrict__ pmax,
                           int first_outer) {
  int gid = blockIdx.x * blockDim.x + threadIdx.x;
  int ch = gid >> 14;
  int rem = gid & (BH - 1);
  size_t base = (size_t)ch * CH2 * BH + rem;
  float c = carry[gid];
  float pm = -1e30f;
  for (int s = 0; s < CH2; s++) {
    size_t idx = base + (size_t)s * BH;
    float fv = f[idx];
    float xv = xt[idx];
    float rv = r[idx];
    float hv = h[idx];
    c = fv * c + (1.f - fv) * xv;
    float o = rv * tanhf(c) + (1.f - rv) * hv;
    h[idx] = o;
    if (DO_MAX) pm = fmaxf(pm, o);
  }
  if (DO_MAX) pmax[gid] = first_outer ? pm : fmaxf(pmax[gid], pm);
}

// ---------------- pool: max over subchunk slots, double tanh ----------------
__global__ void pool_kernel(const float* __restrict__ pmax, float* __restrict__ pooled,
                            int nsub) {
  int rem = blockIdx.x * blockDim.x + threadIdx.x;  // BH
  float m = -1e30f;
  for (int ch = 0; ch < nsub; ch++) m = fmaxf(m, pmax[ch * BH + rem]);
  pooled[rem] = tanhf(tanhf(m));  // max(tanh(h)) == tanh(max(h)) (monotone)
}

// ---------------- final projection (tiny) ----------------
__global__ void out_gemm(const float* __restrict__ pooled, const float* __restrict__ Wc,
                         const float* __restrict__ bc, float* __restrict__ out) {
  __shared__ float pt[H_DIM];
  int b = blockIdx.x;
  for (int i = threadIdx.x; i < H_DIM; i += blockDim.x) pt[i] = pooled[b * H_DIM + i];
  __syncthreads();
  if (threadIdx.x < C_NUM) {
    int c = threadIdx.x;
    float acc = bc[c];
    for (int hh = 0; hh < H_DIM; hh++) acc = fmaf(pt[hh], Wc[hh * C_NUM + c], acc);
    out[b * C_NUM + c] = acc;
  }
}

extern "C" void kernel_launch(void* const* d_in, const int* in_sizes, int n_in,
                              void* d_out, int out_size, void* d_ws, size_t ws_size,
                              hipStream_t stream) {
  const int* x = (const int*)d_in[0];
  const float* embed = (const float*)d_in[1];
  const float* W = (const float*)d_in[2];
  const float* b = (const float*)d_in[3];
  const float* Wc = (const float*)d_in[4];
  const float* bc = (const float*)d_in[5];
  float* out = (float*)d_out;

  const size_t SZ_H = (size_t)M_ROWS * H_DIM * sizeof(float);  // 128 MiB
  const size_t SZ_BH = (size_t)BH * sizeof(float);             // 64 KiB

  // Choose outer time-chunk Sc so the whole layout fits in ws_size.
  // layout: cstate(BH) | pooled(BH) | pmax(nsub*BH) | Ac | Bc | carry (nsub*BH each)
  //         | h (128MiB) | xt | f | r (Sc*BH each)
  int Sc = 32;
  {
    const int cands[6] = {2048, 1024, 512, 256, 128, 64};
    for (int i = 0; i < 6; i++) {
      int c = cands[i];
      size_t nsub = (size_t)c / CH2;
      size_t need = 2 * SZ_BH + 4 * nsub * SZ_BH + SZ_H + 3ull * c * SZ_BH;
      if (need <= ws_size) { Sc = c; break; }
    }
  }
  const int nsub = Sc / CH2;
  const int nouter = S_LEN / Sc;

  char* ws = (char*)d_ws;
  float* cstate = (float*)ws;                 ws += SZ_BH;
  float* pooled = (float*)ws;                 ws += SZ_BH;
  float* pmax   = (float*)ws;                 ws += (size_t)nsub * SZ_BH;
  float* Ac     = (float*)ws;                 ws += (size_t)nsub * SZ_BH;
  float* Bc     = (float*)ws;                 ws += (size_t)nsub * SZ_BH;
  float* carry  = (float*)ws;                 ws += (size_t)nsub * SZ_BH;
  float* h      = (float*)ws;                 ws += SZ_H;
  float* xt     = (float*)ws;                 ws += (size_t)Sc * SZ_BH;
  float* fg     = (float*)ws;                 ws += (size_t)Sc * SZ_BH;
  float* rg     = (float*)ws;

  gather_kernel<<<2048, 256, 0, stream>>>(x, (const float4*)embed, (float4*)h);

  const int scan_blocks = (nsub * BH) / 256;
  for (int l = 0; l < 2; l++) {
    const float* Wl = W + (size_t)l * D_DIM * N_COLS;
    const float* bl = b + (size_t)l * 2 * H_DIM;
    for (int ci = 0; ci < nouter; ci++) {
      const int t0 = ci * Sc;
      float* hc = h + (size_t)t0 * BH;  // rows [t0*B, (t0+Sc)*B)
      sru_gemm<<<(Sc * B_SZ / BM) * (N_COLS / BN), 256, 0, stream>>>(
          hc, Wl, bl, xt, fg, rg);
      scan_pass1<<<scan_blocks, 256, 0, stream>>>(fg, xt, Ac, Bc);
      scan_carry<<<BH / 256, 256, 0, stream>>>(Ac, Bc, carry, cstate, nsub, ci == 0);
      if (l == 0)
        scan_pass2<0><<<scan_blocks, 256, 0, stream>>>(fg, xt, rg, hc, carry, pmax, ci == 0);
      else
        scan_pass2<1><<<scan_blocks, 256, 0, stream>>>(fg, xt, rg, hc, carry, pmax, ci == 0);
    }
  }

  pool_kernel<<<BH / 256, 256, 0, stream>>>(pmax, pooled, nsub);
  out_gemm<<<B_SZ, 256, 0, stream>>>(pooled, Wc, bc, out);
}

// Round 3
// 1125.719 us; speedup vs baseline: 2.4756x; 2.4756x over previous
//
#include <hip/hip_runtime.h>
#include <cmath>

// Problem constants (from reference)
#define S_LEN 2048
#define B_SZ 32
#define D_DIM 512
#define H_DIM 512
#define C_NUM 10
#define M_ROWS (S_LEN * B_SZ)   // 65536
#define BH (B_SZ * H_DIM)       // 16384 (= 2^14)
#define N_COLS (3 * H_DIM)      // 1536
#define CH2 32                  // subchunk length for the parallel scan

typedef __bf16 bf16_t;
typedef bf16_t bf16x8 __attribute__((ext_vector_type(8)));
typedef float f32x4 __attribute__((ext_vector_type(4)));

__device__ __forceinline__ unsigned short f2bf(float f) {
  union { float f; unsigned int u; } a;
  a.f = f;
  unsigned int r = a.u + 0x7FFFu + ((a.u >> 16) & 1u);  // RNE
  return (unsigned short)(r >> 16);
}

__device__ __forceinline__ void load16_lds(const void* g, void* l) {
  __builtin_amdgcn_global_load_lds(
      (const __attribute__((address_space(1))) unsigned int*)g,
      (__attribute__((address_space(3))) unsigned int*)l, 16, 0, 0);
}

// ---------------- gather: h[m][d] = embed[x[m]][d] (fp32 + bf16 copies) ----------------
__global__ void gather_kernel(const int* __restrict__ x,
                              const float4* __restrict__ embed4,
                              float4* __restrict__ h4,
                              ushort4* __restrict__ hb4) {
  int i = blockIdx.x * blockDim.x + threadIdx.x;
  const int total = M_ROWS * (D_DIM / 4);
  int stride = gridDim.x * blockDim.x;
  for (; i < total; i += stride) {
    int m = i >> 7;  // D/4 = 128
    int d = i & 127;
    float4 v = embed4[(size_t)x[m] * 128 + d];
    h4[i] = v;
    hb4[i] = make_ushort4(f2bf(v.x), f2bf(v.y), f2bf(v.z), f2bf(v.w));
  }
}

// ---------------- W -> Wt (transpose + bf16 cast): Wt[l][n][k] = W[l][k][n] ----------------
__global__ void wt_kernel(const float* __restrict__ W, unsigned short* __restrict__ Wt) {
  int idx = blockIdx.x * blockDim.x + threadIdx.x;  // 2 * 1536 * 512
  const int per_l = N_COLS * D_DIM;                 // 786432
  if (idx >= 2 * per_l) return;
  int l = idx / per_l;
  int rem = idx - l * per_l;
  int n = rem >> 9;          // /512
  int k = rem & 511;
  Wt[idx] = f2bf(W[(size_t)l * D_DIM * N_COLS + (size_t)k * N_COLS + n]);
}

// ---------------- bf16 MFMA GEMM + gate epilogue ----------------
// C = A(Mrows x 512) * Wt^T; cols [0,512)->xt, [512,1024)->f=sig(+bf), [1024,1536)->r=sig(+br)
// Tile 128x128, BK=32, 4 waves (2x2), each wave 64x64 = 4x4 frags of 16x16x32.
__global__ __launch_bounds__(256) void sru_gemm_bf16(
    const unsigned short* __restrict__ A,   // Mrows x 512 (bf16 bits)
    const unsigned short* __restrict__ Wt,  // 1536 x 512 (bf16 bits)
    const float* __restrict__ bl,
    float* __restrict__ xt_out, float* __restrict__ f_out, float* __restrict__ r_out) {
  // sub-tiled LDS: As[kc][row][8], 16B row stride -> ~conflict-free ds_read_b128
  __shared__ unsigned short As[4 * 128 * 8];
  __shared__ unsigned short Bs[4 * 128 * 8];
  const int t = threadIdx.x;
  const int wave = t >> 6;
  const int lane = t & 63;
  const int nb = blockIdx.x % (N_COLS / 128);  // 12, fastest -> A-panel L2 reuse
  const int mb = blockIdx.x / (N_COLS / 128);
  const int m0 = mb * 128, n0 = nb * 128;
  const int wm = wave & 1, wn = wave >> 1;
  const int lrow = lane >> 4;  // 0..3 (= kc for frag reads, = row-group for C/D)
  const int lcol = lane & 15;

  f32x4 acc[4][4];
#pragma unroll
  for (int i = 0; i < 4; i++)
#pragma unroll
    for (int j = 0; j < 4; j++) acc[i][j] = (f32x4){0.f, 0.f, 0.f, 0.f};

  // staging: wave w fills kc=w subtile of both As and Bs (2x 1KB each).
  // global src is per-lane; LDS dest is wave-uniform base (+lane*16 by HW).
  const unsigned short* gA0 = A + (size_t)(m0 + lane) * D_DIM + wave * 8;
  const unsigned short* gA1 = A + (size_t)(m0 + 64 + lane) * D_DIM + wave * 8;
  const unsigned short* gB0 = Wt + (size_t)(n0 + lane) * D_DIM + wave * 8;
  const unsigned short* gB1 = Wt + (size_t)(n0 + 64 + lane) * D_DIM + wave * 8;
  unsigned short* lA0 = &As[(wave * 128 + 0) * 8];
  unsigned short* lA1 = &As[(wave * 128 + 64) * 8];
  unsigned short* lB0 = &Bs[(wave * 128 + 0) * 8];
  unsigned short* lB1 = &Bs[(wave * 128 + 64) * 8];

  for (int k0 = 0; k0 < D_DIM; k0 += 32) {
    load16_lds(gA0 + k0, lA0);
    load16_lds(gA1 + k0, lA1);
    load16_lds(gB0 + k0, lB0);
    load16_lds(gB1 + k0, lB1);
    __syncthreads();  // drains vmcnt -> LDS tile ready
    bf16x8 af[4], bfr[4];
#pragma unroll
    for (int mi = 0; mi < 4; mi++)
      af[mi] = *reinterpret_cast<const bf16x8*>(
          &As[(lrow * 128 + wm * 64 + mi * 16 + lcol) * 8]);
#pragma unroll
    for (int ni = 0; ni < 4; ni++)
      bfr[ni] = *reinterpret_cast<const bf16x8*>(
          &Bs[(lrow * 128 + wn * 64 + ni * 16 + lcol) * 8]);
#pragma unroll
    for (int mi = 0; mi < 4; mi++)
#pragma unroll
      for (int ni = 0; ni < 4; ni++)
        acc[mi][ni] =
            __builtin_amdgcn_mfma_f32_16x16x32_bf16(af[mi], bfr[ni], acc[mi][ni], 0, 0, 0);
    __syncthreads();  // reads done before next iter's staging
  }

  // epilogue: D col = lane&15, row = (lane>>4)*4 + reg  [m89-verified]
  const int region = n0 >> 9;  // 0=xt, 1=f, 2=r (BN=128 divides 512)
  float* outp = region == 0 ? xt_out : (region == 1 ? f_out : r_out);
  const int nbase = (n0 & 511) + wn * 64;
  float biasv[4] = {0.f, 0.f, 0.f, 0.f};
  if (region > 0) {
    const float* bptr = bl + (region == 2 ? H_DIM : 0);
#pragma unroll
    for (int ni = 0; ni < 4; ni++) biasv[ni] = bptr[nbase + ni * 16 + lcol];
  }
#pragma unroll
  for (int mi = 0; mi < 4; mi++) {
#pragma unroll
    for (int ni = 0; ni < 4; ni++) {
#pragma unroll
      for (int j = 0; j < 4; j++) {
        int m = m0 + wm * 64 + mi * 16 + lrow * 4 + j;
        int n = nbase + ni * 16 + lcol;
        float v = acc[mi][ni][j];
        if (region > 0) v = 1.f / (1.f + __expf(-(v + biasv[ni])));
        outp[(size_t)m * H_DIM + n] = v;
      }
    }
  }
}

// ---------------- chunk-parallel linear scan over one outer chunk ----------------
__global__ void scan_pass1(const float* __restrict__ f, const float* __restrict__ xt,
                           float* __restrict__ Ac, float* __restrict__ Bc) {
  int gid = blockIdx.x * blockDim.x + threadIdx.x;  // nsub*BH
  int ch = gid >> 14;
  int rem = gid & (BH - 1);
  size_t base = (size_t)ch * CH2 * BH + rem;
  const float* fp = f + base;
  const float* xp = xt + base;
  float Aacc = 1.f, Bacc = 0.f;
#pragma unroll 8
  for (int s = 0; s < CH2; s++) {
    float fv = fp[(size_t)s * BH];
    float xv = xp[(size_t)s * BH];
    Bacc = fv * Bacc + (1.f - fv) * xv;
    Aacc *= fv;
  }
  Ac[gid] = Aacc;
  Bc[gid] = Bacc;
}

__global__ void scan_carry(const float* __restrict__ Ac, const float* __restrict__ Bc,
                           float* __restrict__ carry, float* __restrict__ cstate,
                           int nsub, int first) {
  int rem = blockIdx.x * blockDim.x + threadIdx.x;  // BH
  float c = first ? 0.f : cstate[rem];
  for (int ch = 0; ch < nsub; ch++) {
    int idx = ch * BH + rem;
    carry[idx] = c;
    c = Ac[idx] * c + Bc[idx];
  }
  cstate[rem] = c;
}

// LAST=0: write highway out (fp32 + bf16 for next layer's GEMM). LAST=1: only pmax.
template <int LAST>
__global__ void scan_pass2(const float* __restrict__ f, const float* __restrict__ xt,
                           const float* __restrict__ r, float* __restrict__ h,
                           unsigned short* __restrict__ hb,
                           const float* __restrict__ carry, float* __restrict__ pmax,
                           int first_outer) {
  int gid = blockIdx.x * blockDim.x + threadIdx.x;
  int ch = gid >> 14;
  int rem = gid & (BH - 1);
  size_t base = (size_t)ch * CH2 * BH + rem;
  float c = carry[gid];
  float pm = -1e30f;
  for (int s = 0; s < CH2; s++) {
    size_t idx = base + (size_t)s * BH;
    float fv = f[idx];
    float xv = xt[idx];
    float rv = r[idx];
    float hv = h[idx];
    c = fv * c + (1.f - fv) * xv;
    float o = rv * tanhf(c) + (1.f - rv) * hv;
    if (LAST) {
      pm = fmaxf(pm, o);
    } else {
      h[idx] = o;
      hb[idx] = f2bf(o);
    }
  }
  if (LAST) pmax[gid] = first_outer ? pm : fmaxf(pmax[gid], pm);
}

// ---------------- pool: max over subchunk slots, double tanh ----------------
__global__ void pool_kernel(const float* __restrict__ pmax, float* __restrict__ pooled,
                            int nsub) {
  int rem = blockIdx.x * blockDim.x + threadIdx.x;  // BH
  float m = -1e30f;
  for (int ch = 0; ch < nsub; ch++) m = fmaxf(m, pmax[ch * BH + rem]);
  pooled[rem] = tanhf(tanhf(m));  // max(tanh(h)) == tanh(max(h)) (monotone)
}

// ---------------- final projection (tiny) ----------------
__global__ void out_gemm(const float* __restrict__ pooled, const float* __restrict__ Wc,
                         const float* __restrict__ bc, float* __restrict__ out) {
  __shared__ float pt[H_DIM];
  int b = blockIdx.x;
  for (int i = threadIdx.x; i < H_DIM; i += blockDim.x) pt[i] = pooled[b * H_DIM + i];
  __syncthreads();
  if (threadIdx.x < C_NUM) {
    int c = threadIdx.x;
    float acc = bc[c];
    for (int hh = 0; hh < H_DIM; hh++) acc = fmaf(pt[hh], Wc[hh * C_NUM + c], acc);
    out[b * C_NUM + c] = acc;
  }
}

extern "C" void kernel_launch(void* const* d_in, const int* in_sizes, int n_in,
                              void* d_out, int out_size, void* d_ws, size_t ws_size,
                              hipStream_t stream) {
  const int* x = (const int*)d_in[0];
  const float* embed = (const float*)d_in[1];
  const float* W = (const float*)d_in[2];
  const float* b = (const float*)d_in[3];
  const float* Wc = (const float*)d_in[4];
  const float* bc = (const float*)d_in[5];
  float* out = (float*)d_out;

  const size_t SZ_H = (size_t)M_ROWS * H_DIM * sizeof(float);           // 128 MiB
  const size_t SZ_HB = (size_t)M_ROWS * H_DIM * sizeof(unsigned short); // 64 MiB
  const size_t SZ_WT = 2ull * N_COLS * D_DIM * sizeof(unsigned short);  // 3 MiB
  const size_t SZ_BH = (size_t)BH * sizeof(float);                      // 64 KiB

  // Choose outer time-chunk Sc so the whole layout fits in ws_size.
  int Sc = 32;
  {
    const int cands[7] = {2048, 1024, 512, 256, 128, 64, 32};
    for (int i = 0; i < 7; i++) {
      int c = cands[i];
      size_t nsub = (size_t)c / CH2;
      size_t need = 2 * SZ_BH + 4 * nsub * SZ_BH + SZ_WT + SZ_HB + SZ_H + 3ull * c * SZ_BH;
      if (need <= ws_size) { Sc = c; break; }
    }
  }
  const int nsub = Sc / CH2;
  const int nouter = S_LEN / Sc;

  char* ws = (char*)d_ws;
  float* cstate = (float*)ws;          ws += SZ_BH;
  float* pooled = (float*)ws;          ws += SZ_BH;
  float* pmax   = (float*)ws;          ws += (size_t)nsub * SZ_BH;
  float* Ac     = (float*)ws;          ws += (size_t)nsub * SZ_BH;
  float* Bc     = (float*)ws;          ws += (size_t)nsub * SZ_BH;
  float* carry  = (float*)ws;          ws += (size_t)nsub * SZ_BH;
  unsigned short* Wt = (unsigned short*)ws;  ws += SZ_WT;
  unsigned short* hb = (unsigned short*)ws;  ws += SZ_HB;
  float* h      = (float*)ws;          ws += SZ_H;
  float* xt     = (float*)ws;          ws += (size_t)Sc * SZ_BH;
  float* fg     = (float*)ws;          ws += (size_t)Sc * SZ_BH;
  float* rg     = (float*)ws;

  gather_kernel<<<2048, 256, 0, stream>>>(x, (const float4*)embed, (float4*)h,
                                          (ushort4*)hb);
  wt_kernel<<<(2 * N_COLS * D_DIM + 255) / 256, 256, 0, stream>>>(W, Wt);

  const int scan_blocks = (nsub * BH) / 256;
  const int gemm_blocks = ((Sc * B_SZ) / 128) * (N_COLS / 128);
  for (int l = 0; l < 2; l++) {
    const unsigned short* Wtl = Wt + (size_t)l * N_COLS * D_DIM;
    const float* bl = b + (size_t)l * 2 * H_DIM;
    for (int ci = 0; ci < nouter; ci++) {
      const int t0 = ci * Sc;
      float* hc = h + (size_t)t0 * BH;
      unsigned short* hbc = hb + (size_t)t0 * BH;
      sru_gemm_bf16<<<gemm_blocks, 256, 0, stream>>>(hbc, Wtl, bl, xt, fg, rg);
      scan_pass1<<<scan_blocks, 256, 0, stream>>>(fg, xt, Ac, Bc);
      scan_carry<<<BH / 256, 256, 0, stream>>>(Ac, Bc, carry, cstate, nsub, ci == 0);
      if (l == 0)
        scan_pass2<0><<<scan_blocks, 256, 0, stream>>>(fg, xt, rg, hc, hbc, carry,
                                                       pmax, ci == 0);
      else
        scan_pass2<1><<<scan_blocks, 256, 0, stream>>>(fg, xt, rg, hc, hbc, carry,
                                                       pmax, ci == 0);
    }
  }

  pool_kernel<<<BH / 256, 256, 0, stream>>>(pmax, pooled, nsub);
  out_gemm<<<B_SZ, 256, 0, stream>>>(pooled, Wc, bc, out);
}

// Round 4
// 694.197 us; speedup vs baseline: 4.0145x; 1.6216x over previous
//
#include <hip/hip_runtime.h>
#include <cmath>

// Problem constants (from reference)
#define S_LEN 2048
#define B_SZ 32
#define D_DIM 512
#define H_DIM 512
#define C_NUM 10
#define M_ROWS (S_LEN * B_SZ)   // 65536
#define BH (B_SZ * H_DIM)       // 16384 (= 2^14)
#define N_COLS (3 * H_DIM)      // 1536
#define CH2 32                  // subchunk length for the parallel scan

typedef __bf16 bf16_t;
typedef bf16_t bf16x8 __attribute__((ext_vector_type(8)));
typedef float f32x4 __attribute__((ext_vector_type(4)));
typedef unsigned short ushort_t;

__device__ __forceinline__ unsigned int f2bf(float f) {
  union { float f; unsigned int u; } a;
  a.f = f;
  unsigned int r = a.u + 0x7FFFu + ((a.u >> 16) & 1u);  // RNE
  return r >> 16;
}
__device__ __forceinline__ unsigned int pack2bf(float lo, float hi) {
  return f2bf(lo) | (f2bf(hi) << 16);
}
__device__ __forceinline__ float bflo(unsigned int u) {
  union { unsigned int u; float f; } a; a.u = u << 16; return a.f;
}
__device__ __forceinline__ float bfhi(unsigned int u) {
  union { unsigned int u; float f; } a; a.u = u & 0xffff0000u; return a.f;
}
__device__ __forceinline__ float tanh_fast(float c) {
  float e = __expf(2.f * c);
  return 1.f - 2.f / (e + 1.f);
}
__device__ __forceinline__ void load16_lds(const void* g, void* l) {
  __builtin_amdgcn_global_load_lds(
      (const __attribute__((address_space(1))) unsigned int*)g,
      (__attribute__((address_space(3))) unsigned int*)l, 16, 0, 0);
}

// ---------------- gather: hb[m][d] = bf16(embed[x[m]][d]) ----------------
__global__ void gather_kernel(const int* __restrict__ x,
                              const float4* __restrict__ embed4,
                              uint4* __restrict__ hb4) {
  int i = blockIdx.x * blockDim.x + threadIdx.x;
  const int total = M_ROWS * (D_DIM / 8);
  int stride = gridDim.x * blockDim.x;
  for (; i < total; i += stride) {
    int m = i >> 6;          // D/8 = 64
    int d2 = (i & 63) * 2;   // float4 index
    const float4* src = &embed4[(size_t)x[m] * 128 + d2];
    float4 a = src[0], bq = src[1];
    hb4[i] = make_uint4(pack2bf(a.x, a.y), pack2bf(a.z, a.w),
                        pack2bf(bq.x, bq.y), pack2bf(bq.z, bq.w));
  }
}

// ---------------- W -> Wt (transpose + bf16): Wt[l][n][k] = W[l][k][n] ----------------
__global__ __launch_bounds__(256) void wt_kernel(const float* __restrict__ W,
                                                 ushort_t* __restrict__ Wt) {
  __shared__ float tile[32][33];
  int bid = blockIdx.x;               // 2 * 48 * 16
  int l = bid / 768;
  int rem = bid - l * 768;
  int nblk = rem >> 4, kblk = rem & 15;
  int n0 = nblk * 32, k0 = kblk * 32;
  int tx = threadIdx.x & 31, ty = threadIdx.x >> 5;  // 32 x 8
  const float* Wl = W + (size_t)l * D_DIM * N_COLS;
#pragma unroll
  for (int r = 0; r < 4; r++)
    tile[ty + r * 8][tx] = Wl[(size_t)(k0 + ty + r * 8) * N_COLS + n0 + tx];
  __syncthreads();
  ushort_t* Wtl = Wt + (size_t)l * N_COLS * D_DIM;
#pragma unroll
  for (int r = 0; r < 4; r++)
    Wtl[(size_t)(n0 + ty + r * 8) * D_DIM + k0 + tx] =
        (ushort_t)f2bf(tile[tx][ty + r * 8]);
}

// ---------------- bf16 MFMA GEMM + gate epilogue (bf16 outputs) ----------------
// Tile 128x128, BK=64, 4 waves (2x2), each wave 64x64 = 4x4 frags of 16x16x32.
__global__ __launch_bounds__(256) void sru_gemm_bf16(
    const ushort_t* __restrict__ A,   // rows x 512 (bf16 bits)
    const ushort_t* __restrict__ Wt,  // 1536 x 512 (bf16 bits)
    const float* __restrict__ bl,
    ushort_t* __restrict__ xt_out, ushort_t* __restrict__ f_out,
    ushort_t* __restrict__ r_out) {
  __shared__ ushort_t As[8 * 128 * 8];  // [kc][row][8], kc covers k=[8kc,8kc+8)
  __shared__ ushort_t Bs[8 * 128 * 8];
  const int t = threadIdx.x;
  const int wave = t >> 6, lane = t & 63;
  // bijective XCD swizzle (gridDim.x % 8 == 0 for all our grids)
  const int cpx = gridDim.x >> 3;
  const int swz = (blockIdx.x & 7) * cpx + (blockIdx.x >> 3);
  const int nb = swz % 12, mb = swz / 12;
  const int m0 = mb * 128, n0 = nb * 128;
  const int wm = wave & 1, wn = wave >> 1;
  const int lrow = lane >> 4, lcol = lane & 15;

  f32x4 acc[4][4];
#pragma unroll
  for (int i = 0; i < 4; i++)
#pragma unroll
    for (int j = 0; j < 4; j++) acc[i][j] = (f32x4){0.f, 0.f, 0.f, 0.f};

  for (int k0 = 0; k0 < D_DIM; k0 += 64) {
    // wave stages kc = {2w, 2w+1} of both As and Bs (8 loads/wave)
#pragma unroll
    for (int j = 0; j < 2; j++) {
      const int kc = wave * 2 + j;
#pragma unroll
      for (int half = 0; half < 2; half++) {
        load16_lds(A + (size_t)(m0 + half * 64 + lane) * D_DIM + k0 + kc * 8,
                   &As[((kc)*128 + half * 64) * 8]);
        load16_lds(Wt + (size_t)(n0 + half * 64 + lane) * D_DIM + k0 + kc * 8,
                   &Bs[((kc)*128 + half * 64) * 8]);
      }
    }
    __syncthreads();  // drains vmcnt -> LDS tile ready
    bf16x8 af[2][4], bfr[2][4];
#pragma unroll
    for (int ks = 0; ks < 2; ks++) {
#pragma unroll
      for (int mi = 0; mi < 4; mi++)
        af[ks][mi] = *reinterpret_cast<const bf16x8*>(
            &As[((ks * 4 + lrow) * 128 + wm * 64 + mi * 16 + lcol) * 8]);
#pragma unroll
      for (int ni = 0; ni < 4; ni++)
        bfr[ks][ni] = *reinterpret_cast<const bf16x8*>(
            &Bs[((ks * 4 + lrow) * 128 + wn * 64 + ni * 16 + lcol) * 8]);
    }
#pragma unroll
    for (int ks = 0; ks < 2; ks++)
#pragma unroll
      for (int mi = 0; mi < 4; mi++)
#pragma unroll
        for (int ni = 0; ni < 4; ni++)
          acc[mi][ni] = __builtin_amdgcn_mfma_f32_16x16x32_bf16(
              af[ks][mi], bfr[ks][ni], acc[mi][ni], 0, 0, 0);
    __syncthreads();  // reads done before next iter's staging
  }

  // epilogue: D col = lane&15, row = (lane>>4)*4 + reg
  const int region = n0 >> 9;  // 0=xt, 1=f, 2=r
  ushort_t* outp = region == 0 ? xt_out : (region == 1 ? f_out : r_out);
  const int nbase = (n0 & 511) + wn * 64;
  float biasv[4] = {0.f, 0.f, 0.f, 0.f};
  if (region > 0) {
    const float* bptr = bl + (region == 2 ? H_DIM : 0);
#pragma unroll
    for (int ni = 0; ni < 4; ni++) biasv[ni] = bptr[nbase + ni * 16 + lcol];
  }
#pragma unroll
  for (int mi = 0; mi < 4; mi++) {
#pragma unroll
    for (int ni = 0; ni < 4; ni++) {
#pragma unroll
      for (int j = 0; j < 4; j++) {
        int m = m0 + wm * 64 + mi * 16 + lrow * 4 + j;
        int n = nbase + ni * 16 + lcol;
        float v = acc[mi][ni][j];
        if (region > 0) v = 1.f / (1.f + __expf(-(v + biasv[ni])));
        outp[(size_t)m * H_DIM + n] = (ushort_t)f2bf(v);
      }
    }
  }
}

// ---------------- chunk-parallel linear scan (bf16 gates, x2 columns/thread) ----------------
__global__ void scan_pass1(const ushort_t* __restrict__ f, const ushort_t* __restrict__ xt,
                           float* __restrict__ Ac, float* __restrict__ Bc) {
  int gid = blockIdx.x * blockDim.x + threadIdx.x;  // nsub * BH/2
  int ch = gid >> 13;
  int col = (gid & 8191) * 2;
  size_t base = (size_t)ch * CH2 * BH + col;
  float A0 = 1.f, A1 = 1.f, B0 = 0.f, B1 = 0.f;
#pragma unroll 8
  for (int s = 0; s < CH2; s++) {
    unsigned int fv = *(const unsigned int*)&f[base + (size_t)s * BH];
    unsigned int xv = *(const unsigned int*)&xt[base + (size_t)s * BH];
    float f0 = bflo(fv), f1 = bfhi(fv);
    float x0 = bflo(xv), x1 = bfhi(xv);
    B0 = f0 * B0 + (1.f - f0) * x0;
    B1 = f1 * B1 + (1.f - f1) * x1;
    A0 *= f0;
    A1 *= f1;
  }
  int o = ch * BH + col;
  *(float2*)&Ac[o] = make_float2(A0, A1);
  *(float2*)&Bc[o] = make_float2(B0, B1);
}

__global__ void scan_carry(const float* __restrict__ Ac, const float* __restrict__ Bc,
                           float* __restrict__ carry, float* __restrict__ cstate,
                           int nsub, int first) {
  int rem = blockIdx.x * blockDim.x + threadIdx.x;  // BH
  float c = first ? 0.f : cstate[rem];
  for (int ch = 0; ch < nsub; ch++) {
    int idx = ch * BH + rem;
    carry[idx] = c;
    c = Ac[idx] * c + Bc[idx];
  }
  cstate[rem] = c;
}

// LAST=0: write highway out (bf16, may alias xt in-place). LAST=1: only pmax.
template <int LAST>
__global__ void scan_pass2(const ushort_t* __restrict__ f, const ushort_t* __restrict__ xt,
                           const ushort_t* __restrict__ r, const ushort_t* __restrict__ hw,
                           ushort_t* __restrict__ ob,
                           const float* __restrict__ carry, float* __restrict__ pmax,
                           int first_outer) {
  int gid = blockIdx.x * blockDim.x + threadIdx.x;  // nsub * BH/2
  int ch = gid >> 13;
  int col = (gid & 8191) * 2;
  size_t base = (size_t)ch * CH2 * BH + col;
  float2 cc = *(const float2*)&carry[ch * BH + col];
  float c0 = cc.x, c1 = cc.y;
  float pm0 = -1e30f, pm1 = -1e30f;
  for (int s = 0; s < CH2; s++) {
    size_t idx = base + (size_t)s * BH;
    unsigned int fv = *(const unsigned int*)&f[idx];
    unsigned int xv = *(const unsigned int*)&xt[idx];
    unsigned int rv = *(const unsigned int*)&r[idx];
    unsigned int hv = *(const unsigned int*)&hw[idx];
    float f0 = bflo(fv), f1 = bfhi(fv);
    float x0 = bflo(xv), x1 = bfhi(xv);
    float r0 = bflo(rv), r1 = bfhi(rv);
    float h0 = bflo(hv), h1 = bfhi(hv);
    c0 = f0 * c0 + (1.f - f0) * x0;
    c1 = f1 * c1 + (1.f - f1) * x1;
    float o0 = r0 * tanh_fast(c0) + (1.f - r0) * h0;
    float o1 = r1 * tanh_fast(c1) + (1.f - r1) * h1;
    if (LAST) {
      pm0 = fmaxf(pm0, o0);
      pm1 = fmaxf(pm1, o1);
    } else {
      *(unsigned int*)&ob[idx] = pack2bf(o0, o1);
    }
  }
  if (LAST) {
    int o = ch * BH + col;
    if (first_outer) {
      *(float2*)&pmax[o] = make_float2(pm0, pm1);
    } else {
      pmax[o] = fmaxf(pmax[o], pm0);
      pmax[o + 1] = fmaxf(pmax[o + 1], pm1);
    }
  }
}

// ---------------- pool: max over subchunk slots, double tanh ----------------
__global__ void pool_kernel(const float* __restrict__ pmax, float* __restrict__ pooled,
                            int nsub) {
  int rem = blockIdx.x * blockDim.x + threadIdx.x;  // BH
  float m = -1e30f;
  for (int ch = 0; ch < nsub; ch++) m = fmaxf(m, pmax[ch * BH + rem]);
  pooled[rem] = tanhf(tanhf(m));  // max(tanh(h)) == tanh(max(h)) (monotone)
}

// ---------------- final projection (tiny) ----------------
__global__ void out_gemm(const float* __restrict__ pooled, const float* __restrict__ Wc,
                         const float* __restrict__ bc, float* __restrict__ out) {
  __shared__ float pt[H_DIM];
  int b = blockIdx.x;
  for (int i = threadIdx.x; i < H_DIM; i += blockDim.x) pt[i] = pooled[b * H_DIM + i];
  __syncthreads();
  if (threadIdx.x < C_NUM) {
    int c = threadIdx.x;
    float acc = bc[c];
    for (int hh = 0; hh < H_DIM; hh++) acc = fmaf(pt[hh], Wc[hh * C_NUM + c], acc);
    out[b * C_NUM + c] = acc;
  }
}

extern "C" void kernel_launch(void* const* d_in, const int* in_sizes, int n_in,
                              void* d_out, int out_size, void* d_ws, size_t ws_size,
                              hipStream_t stream) {
  const int* x = (const int*)d_in[0];
  const float* embed = (const float*)d_in[1];
  const float* W = (const float*)d_in[2];
  const float* b = (const float*)d_in[3];
  const float* Wc = (const float*)d_in[4];
  const float* bc = (const float*)d_in[5];
  float* out = (float*)d_out;

  const size_t SZ_HB = (size_t)M_ROWS * H_DIM * 2;   // 64 MiB (bf16 full-S plane)
  const size_t SZ_WT = 2ull * N_COLS * D_DIM * 2;    // 3 MiB
  const size_t SZ_BHf = (size_t)BH * 4;              // 64 KiB

  // mode select: full-S (preferred) or chunked fallback
  int Sc = 0;
  {
    size_t nsubF = S_LEN / CH2;  // 64
    size_t need_full = 4 * SZ_HB + 4 * nsubF * SZ_BHf + SZ_WT + 2 * SZ_BHf;  // ~275 MB
    if (need_full <= ws_size) {
      Sc = S_LEN;
    } else {
      const int cands[6] = {1024, 512, 256, 128, 64, 32};
      for (int i = 0; i < 6; i++) {
        int c = cands[i];
        size_t nsub = (size_t)c / CH2;
        size_t need = 2 * SZ_HB + 3ull * c * BH * 2 + 4 * nsub * SZ_BHf + SZ_WT + 2 * SZ_BHf;
        if (need <= ws_size) { Sc = c; break; }
      }
      if (Sc == 0) Sc = 32;
    }
  }
  const int full = (Sc == S_LEN);
  const int nsub = Sc / CH2;
  const int nouter = S_LEN / Sc;

  char* p = (char*)d_ws;
  float* cstate = (float*)p; p += SZ_BHf;
  float* pooled = (float*)p; p += SZ_BHf;
  float* pmax   = (float*)p; p += (size_t)nsub * SZ_BHf;
  float* Ac     = (float*)p; p += (size_t)nsub * SZ_BHf;
  float* Bc     = (float*)p; p += (size_t)nsub * SZ_BHf;
  float* carry  = (float*)p; p += (size_t)nsub * SZ_BHf;
  ushort_t* Wt  = (ushort_t*)p; p += SZ_WT;
  ushort_t* hb  = (ushort_t*)p; p += SZ_HB;
  ushort_t* ob = nullptr;
  if (!full) { ob = (ushort_t*)p; p += SZ_HB; }
  const size_t SZ_G = full ? SZ_HB : (size_t)Sc * BH * 2;
  ushort_t* G1 = (ushort_t*)p; p += SZ_G;
  ushort_t* G2 = (ushort_t*)p; p += SZ_G;
  ushort_t* G3 = (ushort_t*)p;

  gather_kernel<<<2048, 256, 0, stream>>>(x, (const float4*)embed, (uint4*)hb);
  wt_kernel<<<1536, 256, 0, stream>>>(W, Wt);

  const int p1_blocks = (nsub * (BH / 2)) / 256;
  const int gemm_blocks = ((Sc * B_SZ) / 128) * (N_COLS / 128);
  for (int l = 0; l < 2; l++) {
    const ushort_t* Wtl = Wt + (size_t)l * N_COLS * D_DIM;
    const float* bl = b + (size_t)l * 2 * H_DIM;
    for (int ci = 0; ci < nouter; ci++) {
      const size_t off = (size_t)ci * Sc * BH;
      const ushort_t* Ain;
      ushort_t *xtd = G1, *fd = G2, *rd = G3;
      if (full) {
        if (l == 0) { Ain = hb; }
        else        { Ain = G1; xtd = hb; }  // layer-1 xt gate into dead hb
      } else {
        Ain = (l == 0 ? hb : ob) + off;
      }
      sru_gemm_bf16<<<gemm_blocks, 256, 0, stream>>>(Ain, Wtl, bl, xtd, fd, rd);
      scan_pass1<<<p1_blocks, 256, 0, stream>>>(fd, xtd, Ac, Bc);
      scan_carry<<<BH / 256, 256, 0, stream>>>(Ac, Bc, carry, cstate, nsub, ci == 0);
      if (l == 0) {
        const ushort_t* hwp = full ? hb : hb + off;
        ushort_t* obp = full ? G1 : ob + off;  // full mode: in-place over xt
        scan_pass2<0><<<p1_blocks, 256, 0, stream>>>(fd, xtd, rd, hwp, obp, carry,
                                                     pmax, ci == 0);
      } else {
        const ushort_t* hwp = full ? G1 : ob + off;
        scan_pass2<1><<<p1_blocks, 256, 0, stream>>>(fd, xtd, rd, hwp, nullptr, carry,
                                                     pmax, ci == 0);
      }
    }
  }

  pool_kernel<<<BH / 256, 256, 0, stream>>>(pmax, pooled, nsub);
  out_gemm<<<B_SZ, 256, 0, stream>>>(pooled, Wc, bc, out);
}